// Round 1
// baseline (2692.281 us; speedup 1.0000x reference)
//
#include <hip/hip_runtime.h>
#include <hip/hip_bf16.h>

// Problem constants (reference: B=2, C=512, GROUPS=32, H=W=64)
#define CH     512
#define NGROUP 32
#define CPG    16        // channels per group
#define NPIX   4096      // H*W
#define BATCH  2
#define BI     16        // flash: query rows per block
#define BJ     64        // flash: key cols per j-block

// ---------------------------------------------------------------------------
// GroupNorm: one block per (batch, group). 16 ch x 4096 px = 65536 floats.
// ---------------------------------------------------------------------------
__global__ __launch_bounds__(256) void gn_kernel(
    const float* __restrict__ x, const float* __restrict__ w,
    const float* __restrict__ b, float* __restrict__ h) {
  int bg = blockIdx.x;
  int batch = bg >> 5, g = bg & 31;
  const float* xp = x + ((size_t)batch * CH + (size_t)g * CPG) * NPIX;
  float* hp = h + ((size_t)batch * CH + (size_t)g * CPG) * NPIX;
  int t = threadIdx.x;
  const float4* x4 = (const float4*)xp;
  float s = 0.f, ss = 0.f;
  for (int i = t; i < CPG * NPIX / 4; i += 256) {
    float4 v = x4[i];
    s += v.x + v.y + v.z + v.w;
    ss += v.x * v.x + v.y * v.y + v.z * v.z + v.w * v.w;
  }
  __shared__ float rs[4], rss[4], stat[2];
  for (int off = 32; off > 0; off >>= 1) {
    s += __shfl_down(s, off);
    ss += __shfl_down(ss, off);
  }
  if ((t & 63) == 0) { rs[t >> 6] = s; rss[t >> 6] = ss; }
  __syncthreads();
  if (t == 0) {
    float S = rs[0] + rs[1] + rs[2] + rs[3];
    float SS = rss[0] + rss[1] + rss[2] + rss[3];
    float mean = S * (1.f / (CPG * NPIX));
    float var = SS * (1.f / (CPG * NPIX)) - mean * mean;
    stat[0] = mean;
    stat[1] = rsqrtf(var + 1e-6f);
  }
  __syncthreads();
  float mean = stat[0], rstd = stat[1];
  float4* h4 = (float4*)hp;
  for (int i = t; i < CPG * NPIX / 4; i += 256) {
    int c = g * CPG + (i >> 10);          // i*4/4096
    float wc = w[c] * rstd, bc = b[c];
    float4 v = x4[i];
    float4 o;
    o.x = (v.x - mean) * wc + bc;
    o.y = (v.y - mean) * wc + bc;
    o.z = (v.z - mean) * wc + bc;
    o.w = (v.w - mean) * wc + bc;
    h4[i] = o;
  }
}

// ---------------------------------------------------------------------------
// 1x1 conv == GEMM: out[b,o,n] = sum_c W[o,c] * in[b,c,n] + bias[o] (+res)
// 64x64 tile, 256 threads, 4x4 per thread, K-chunk 16.
// ---------------------------------------------------------------------------
template <bool RES>
__global__ __launch_bounds__(256) void conv_gemm(
    const float* __restrict__ W, const float* __restrict__ bias,
    const float* __restrict__ in, const float* __restrict__ res,
    float* __restrict__ out) {
  int nb = blockIdx.x * 64;
  int mb = blockIdx.y * 64;
  int bat = blockIdx.z;
  const float* inp = in + (size_t)bat * CH * NPIX;
  float* outp = out + (size_t)bat * CH * NPIX;
  __shared__ float At[16][68];   // [k][m]
  __shared__ float Bt[16][68];   // [k][n]
  int t = threadIdx.x;
  int tx = t & 15, ty = t >> 4;
  float acc[4][4] = {};
  for (int k0 = 0; k0 < CH; k0 += 16) {
    {
      int m = t >> 2, kq = (t & 3) * 4;
      float4 wv = *(const float4*)&W[(size_t)(mb + m) * CH + k0 + kq];
      At[kq + 0][m] = wv.x;
      At[kq + 1][m] = wv.y;
      At[kq + 2][m] = wv.z;
      At[kq + 3][m] = wv.w;
      int kb = t >> 4, n = (t & 15) * 4;
      *(float4*)&Bt[kb][n] = *(const float4*)&inp[(size_t)(k0 + kb) * NPIX + nb + n];
    }
    __syncthreads();
#pragma unroll
    for (int kk = 0; kk < 16; ++kk) {
      float4 a = *(const float4*)&At[kk][ty * 4];
      float4 bv = *(const float4*)&Bt[kk][tx * 4];
      acc[0][0] += a.x * bv.x; acc[0][1] += a.x * bv.y; acc[0][2] += a.x * bv.z; acc[0][3] += a.x * bv.w;
      acc[1][0] += a.y * bv.x; acc[1][1] += a.y * bv.y; acc[1][2] += a.y * bv.z; acc[1][3] += a.y * bv.w;
      acc[2][0] += a.z * bv.x; acc[2][1] += a.z * bv.y; acc[2][2] += a.z * bv.z; acc[2][3] += a.z * bv.w;
      acc[3][0] += a.w * bv.x; acc[3][1] += a.w * bv.y; acc[3][2] += a.w * bv.z; acc[3][3] += a.w * bv.w;
    }
    __syncthreads();
  }
#pragma unroll
  for (int i = 0; i < 4; ++i) {
    int m = mb + ty * 4 + i;
    float bb = bias[m];
    size_t off = (size_t)m * NPIX + nb + tx * 4;
    float4 o;
    o.x = acc[i][0] + bb; o.y = acc[i][1] + bb;
    o.z = acc[i][2] + bb; o.w = acc[i][3] + bb;
    if (RES) {
      float4 r = *(const float4*)&res[(size_t)bat * CH * NPIX + off];
      o.x += r.x; o.y += r.y; o.z += r.z; o.w += r.w;
    }
    *(float4*)&outp[off] = o;
  }
}

// ---------------------------------------------------------------------------
// Flash attention, fp32, single pass with online softmax.
// Block = (batch, 16 query rows). S tile 16x64 (2x2/thread), O acc 32 f32/thr.
// q,k,v layout: [B][C][N].  out = softmax(Q^T K / sqrt(C)) applied to V:
// out[c][i] = sum_j P[i][j] V[c][j].
// ---------------------------------------------------------------------------
__global__ __launch_bounds__(256) void flash_kernel(
    const float* __restrict__ q, const float* __restrict__ k,
    const float* __restrict__ v, float* __restrict__ out) {
  int i0 = blockIdx.x * BI;
  int b = blockIdx.y;
  const float* qb = q + (size_t)b * CH * NPIX;
  const float* kb = k + (size_t)b * CH * NPIX;
  const float* vb = v + (size_t)b * CH * NPIX;
  float* ob = out + (size_t)b * CH * NPIX;

  __shared__ float Qs[CH][BI];        // [c][i]   32 KB
  __shared__ float KV[64 * 68];       // Ks [cc][j] | Vs [j][cc]  17 KB (union)
  __shared__ float Ps[BJ][BI + 2];    // [j][i]
  __shared__ float red[BI][33];
  __shared__ float rowm[BI], rowl[BI], rowa[BI];

  int t = threadIdx.x;

  // stage full Q block
  for (int it = 0; it < CH / 16; ++it) {
    int c = it * 16 + (t >> 4);
    Qs[c][t & 15] = qb[(size_t)c * NPIX + i0 + (t & 15)];
  }
  if (t < BI) { rowm[t] = -1e30f; rowl[t] = 0.f; }

  float acc[8][4] = {};   // O: i = t>>4, c = ch*64 + (t&15)*4 + r
  const float scale = 0.044194173824159216f;  // 512^-0.5
  int sty = t >> 5, stx = t & 31;             // S tile: i=2*sty+{0,1}, j=2*stx+{0,1}
  int iO = t >> 4, cO = (t & 15) * 4;

  __syncthreads();

  for (int j0 = 0; j0 < NPIX; j0 += BJ) {
    // ---- S = Q^T K (chunked over c)
    float s00 = 0.f, s01 = 0.f, s10 = 0.f, s11 = 0.f;
    for (int c0 = 0; c0 < CH; c0 += 64) {
      __syncthreads();
      {
        int cc = t >> 2, jj = (t & 3) * 16;
        const float* src = kb + (size_t)(c0 + cc) * NPIX + j0 + jj;
        float* dst = &KV[cc * 68 + jj];
        *(float4*)(dst + 0)  = *(const float4*)(src + 0);
        *(float4*)(dst + 4)  = *(const float4*)(src + 4);
        *(float4*)(dst + 8)  = *(const float4*)(src + 8);
        *(float4*)(dst + 12) = *(const float4*)(src + 12);
      }
      __syncthreads();
#pragma unroll 8
      for (int cc = 0; cc < 64; ++cc) {
        float2 qv = *(const float2*)&Qs[c0 + cc][sty * 2];
        float2 kv = *(const float2*)&KV[cc * 68 + stx * 2];
        s00 += qv.x * kv.x; s01 += qv.x * kv.y;
        s10 += qv.y * kv.x; s11 += qv.y * kv.y;
      }
    }
    s00 *= scale; s01 *= scale; s10 *= scale; s11 *= scale;

    // ---- online softmax
    red[sty * 2 + 0][stx] = fmaxf(s00, s01);
    red[sty * 2 + 1][stx] = fmaxf(s10, s11);
    __syncthreads();
    if (t < BI) {
      float m = red[t][0];
      for (int xx = 1; xx < 32; ++xx) m = fmaxf(m, red[t][xx]);
      float mold = rowm[t];
      float mnew = fmaxf(mold, m);
      rowa[t] = __expf(mold - mnew);
      rowm[t] = mnew;
    }
    __syncthreads();
    float m0 = rowm[sty * 2 + 0], m1 = rowm[sty * 2 + 1];
    float p00 = __expf(s00 - m0), p01 = __expf(s01 - m0);
    float p10 = __expf(s10 - m1), p11 = __expf(s11 - m1);
    Ps[stx * 2 + 0][sty * 2 + 0] = p00;
    Ps[stx * 2 + 1][sty * 2 + 0] = p01;
    Ps[stx * 2 + 0][sty * 2 + 1] = p10;
    Ps[stx * 2 + 1][sty * 2 + 1] = p11;
    red[sty * 2 + 0][stx] = p00 + p01;
    red[sty * 2 + 1][stx] = p10 + p11;
    __syncthreads();
    if (t < BI) {
      float ssum = 0.f;
      for (int xx = 0; xx < 32; ++xx) ssum += red[t][xx];
      rowl[t] = rowl[t] * rowa[t] + ssum;
    }
    __syncthreads();
    float alpha = rowa[iO];
#pragma unroll
    for (int ch = 0; ch < 8; ++ch)
#pragma unroll
      for (int r = 0; r < 4; ++r) acc[ch][r] *= alpha;

    // ---- O += P * V^T (chunked over c)
#pragma unroll
    for (int ch = 0; ch < 8; ++ch) {
      __syncthreads();
      {
        int cc = t >> 2, jj = (t & 3) * 16;
        const float* src = vb + (size_t)(ch * 64 + cc) * NPIX + j0 + jj;
        float4 a0 = *(const float4*)(src + 0);
        float4 a1 = *(const float4*)(src + 4);
        float4 a2 = *(const float4*)(src + 8);
        float4 a3 = *(const float4*)(src + 12);
        float tmp[16] = {a0.x, a0.y, a0.z, a0.w, a1.x, a1.y, a1.z, a1.w,
                         a2.x, a2.y, a2.z, a2.w, a3.x, a3.y, a3.z, a3.w};
#pragma unroll
        for (int xx = 0; xx < 16; ++xx) KV[(jj + xx) * 68 + cc] = tmp[xx];
      }
      __syncthreads();
#pragma unroll 4
      for (int j = 0; j < BJ; ++j) {
        float p = Ps[j][iO];
        float4 vv = *(const float4*)&KV[j * 68 + cO];
        acc[ch][0] += p * vv.x;
        acc[ch][1] += p * vv.y;
        acc[ch][2] += p * vv.z;
        acc[ch][3] += p * vv.w;
      }
    }
  }
  float invl = 1.f / rowl[iO];
#pragma unroll
  for (int ch = 0; ch < 8; ++ch)
#pragma unroll
    for (int r = 0; r < 4; ++r)
      ob[(size_t)(ch * 64 + cO + r) * NPIX + i0 + iO] = acc[ch][r] * invl;
}

// ---------------------------------------------------------------------------
extern "C" void kernel_launch(void* const* d_in, const int* in_sizes, int n_in,
                              void* d_out, int out_size, void* d_ws, size_t ws_size,
                              hipStream_t stream) {
  (void)in_sizes; (void)n_in; (void)out_size; (void)ws_size;
  const float* x   = (const float*)d_in[0];
  const float* gnw = (const float*)d_in[1];
  const float* gnb = (const float*)d_in[2];
  const float* wq  = (const float*)d_in[3];
  const float* bq  = (const float*)d_in[4];
  const float* wk  = (const float*)d_in[5];
  const float* bk  = (const float*)d_in[6];
  const float* wv  = (const float*)d_in[7];
  const float* bv  = (const float*)d_in[8];
  const float* wo  = (const float*)d_in[9];
  const float* bo  = (const float*)d_in[10];
  float* out = (float*)d_out;

  const size_t TEN = (size_t)BATCH * CH * NPIX;  // 4 Mi floats = 16 MB
  float* h  = (float*)d_ws;      // ws usage: 4 * 16 MB = 64 MB
  float* q  = h + TEN;
  float* k  = q + TEN;
  float* v  = k + TEN;
  float* ao = h;                 // h is dead after v is computed — alias

  gn_kernel<<<dim3(BATCH * NGROUP), 256, 0, stream>>>(x, gnw, gnb, h);
  dim3 cgrid(NPIX / 64, CH / 64, BATCH);
  conv_gemm<false><<<cgrid, 256, 0, stream>>>(wq, bq, h, nullptr, q);
  conv_gemm<false><<<cgrid, 256, 0, stream>>>(wk, bk, h, nullptr, k);
  conv_gemm<false><<<cgrid, 256, 0, stream>>>(wv, bv, h, nullptr, v);
  flash_kernel<<<dim3(NPIX / BI, BATCH), 256, 0, stream>>>(q, k, v, ao);
  conv_gemm<true><<<cgrid, 256, 0, stream>>>(wo, bo, ao, x, out);
}

// Round 2
// 558.344 us; speedup vs baseline: 4.8219x; 4.8219x over previous
//
#include <hip/hip_runtime.h>

// B=2, C=512, GROUPS=32, H=W=64, N=4096 pixels. All heavy math in bf16 MFMA.
//
// ws layout (bf16 unless noted):
//   ht  [8192 pix][512 c]      @ 0         (GN output, pixel-major)
//   QKt [8192 pix][1024]       @ 8  MB     (cols 0-511 = q, 512-1023 = k)
//   Vg  [512 c][8192 pix]      @ 24 MB     (channel-major: PV B-operand wants k=j contiguous)
//   AOt [8192 pix][512 c]      @ 32 MB     (attention out)
//   Wqk [1024][512], Wv/Wo [512][512], Bqk fp32[1024]  @ 40 MB+

typedef __attribute__((ext_vector_type(8))) short bf16x8;
typedef __attribute__((ext_vector_type(4))) float f32x4;
typedef unsigned short u16;
typedef unsigned int u32;

__device__ __forceinline__ u16 f2bf(float f) {
  u32 u = __builtin_bit_cast(u32, f);
  return (u16)((u + 0x7FFFu + ((u >> 16) & 1u)) >> 16);
}

// async 16 B/lane global->LDS; LDS dst wave-uniform base + lane*16
__device__ __forceinline__ void gll16(const void* g, void* l) {
  __builtin_amdgcn_global_load_lds((const __attribute__((address_space(1))) u32*)g,
                                   (__attribute__((address_space(3))) u32*)l, 16, 0, 0);
}

// ---------------------------------------------------------------------------
// GroupNorm: block per (batch, group); stats fp32, output bf16 TRANSPOSED to
// [pix][512] so conv GEMMs read it as A/B operand rows directly.
// ---------------------------------------------------------------------------
__global__ __launch_bounds__(256) void gn_kernel(
    const float* __restrict__ x, const float* __restrict__ w,
    const float* __restrict__ b, u16* __restrict__ ht) {
  int bg = blockIdx.x;
  int batch = bg >> 5, g = bg & 31;
  const float* xp = x + ((size_t)batch * 512 + (size_t)g * 16) * 4096;
  int t = threadIdx.x;
  const float4* x4 = (const float4*)xp;
  float s = 0.f, ss = 0.f;
  for (int i = t; i < 16384; i += 256) {
    float4 v = x4[i];
    s += v.x + v.y + v.z + v.w;
    ss += v.x * v.x + v.y * v.y + v.z * v.z + v.w * v.w;
  }
  __shared__ float rs[4], rss[4], stat[2];
  for (int off = 32; off > 0; off >>= 1) {
    s += __shfl_down(s, off);
    ss += __shfl_down(ss, off);
  }
  if ((t & 63) == 0) { rs[t >> 6] = s; rss[t >> 6] = ss; }
  __syncthreads();
  if (t == 0) {
    float S = rs[0] + rs[1] + rs[2] + rs[3];
    float SS = rss[0] + rss[1] + rss[2] + rss[3];
    float mean = S * (1.f / 65536.f);
    float var = SS * (1.f / 65536.f) - mean * mean;
    stat[0] = mean;
    stat[1] = rsqrtf(var + 1e-6f);
  }
  __syncthreads();
  float mean = stat[0], rstd = stat[1];
  float wsc[16], bsc[16];
#pragma unroll
  for (int cc = 0; cc < 16; ++cc) {
    float wv = w[g * 16 + cc];
    wsc[cc] = wv * rstd;
    bsc[cc] = b[g * 16 + cc] - mean * wsc[cc];
  }
  u16* hp = ht + (size_t)batch * 4096 * 512 + g * 16;
  for (int n = t; n < 4096; n += 256) {
    union { u16 pk[16]; uint4 v4[2]; } u;
#pragma unroll
    for (int cc = 0; cc < 16; ++cc)
      u.pk[cc] = f2bf(xp[cc * 4096 + n] * wsc[cc] + bsc[cc]);
    uint4* dst = (uint4*)(hp + (size_t)n * 512);
    dst[0] = u.v4[0];
    dst[1] = u.v4[1];
  }
}

// ---------------------------------------------------------------------------
// Weight/bias conversion: fp32 -> bf16, stack wq|wk into one [1024][512].
// ---------------------------------------------------------------------------
__global__ __launch_bounds__(256) void wcvt_kernel(
    const float* __restrict__ wq, const float* __restrict__ wk,
    const float* __restrict__ wv, const float* __restrict__ wo,
    const float* __restrict__ bq, const float* __restrict__ bk,
    u16* __restrict__ Wqk, u16* __restrict__ Wv, u16* __restrict__ Wo,
    float* __restrict__ Bqk) {
  int i = blockIdx.x * 256 + threadIdx.x;  // grid 1024 -> 262144
  Wqk[i] = f2bf(wq[i]);
  Wqk[262144 + i] = f2bf(wk[i]);
  Wv[i] = f2bf(wv[i]);
  Wo[i] = f2bf(wo[i]);
  if (i < 512) { Bqk[i] = bq[i]; Bqk[512 + i] = bk[i]; }
}

// ---------------------------------------------------------------------------
// TN MFMA GEMM: D[m][n] = sum_k A[m][k]*B[n][k]. 128x128 block tile, 4 waves
// 2x2, 4x4 16x16 tiles/wave, BK=64, global_load_lds staging into
// [kc][row] interleaved LDS (16B chunks; conflict-free b128 frag reads).
// MODE 0: bf16 out, bias over n.  MODE 1: bf16 out, bias over m.
// MODE 2: fp32 out at ((n>>12)*512+m)*4096+(n&4095), bias over m, +residual.
// ---------------------------------------------------------------------------
template <int MODE>
__global__ __launch_bounds__(256) void mfma_gemm(
    const u16* __restrict__ A, int sA, const u16* __restrict__ B, int sB,
    const float* __restrict__ bias, const float* __restrict__ res,
    void* __restrict__ out, int ostr) {
  __shared__ char sm[32768];
  char* As = sm;           // [kc8][m128] 16B units
  char* Bs = sm + 16384;   // [kc8][n128]
  int t = threadIdx.x;
  int w = t >> 6, lane = t & 63, quad = lane >> 4, ln = lane & 15;
  int wm = w >> 1, wn = w & 1;
  int m0 = blockIdx.y * 128, n0 = blockIdx.x * 128;
  f32x4 acc[4][4] = {};

  int srow[4], skc[4];
#pragma unroll
  for (int si = 0; si < 4; ++si) {
    int s = (w * 4 + si) * 64 + lane;
    srow[si] = s & 127;
    skc[si] = s >> 7;
  }

  for (int k0 = 0; k0 < 512; k0 += 64) {
#pragma unroll
    for (int si = 0; si < 4; ++si) {
      gll16(A + (size_t)(m0 + srow[si]) * sA + k0 + skc[si] * 8, As + (w * 4 + si) * 1024);
      gll16(B + (size_t)(n0 + srow[si]) * sB + k0 + skc[si] * 8, Bs + (w * 4 + si) * 1024);
    }
    __syncthreads();
#pragma unroll
    for (int ks = 0; ks < 2; ++ks) {
      bf16x8 af[4], bfr[4];
#pragma unroll
      for (int tm = 0; tm < 4; ++tm)
        af[tm] = *(const bf16x8*)(As + (((ks * 4 + quad) * 128) + wm * 64 + tm * 16 + ln) * 16);
#pragma unroll
      for (int tn = 0; tn < 4; ++tn)
        bfr[tn] = *(const bf16x8*)(Bs + (((ks * 4 + quad) * 128) + wn * 64 + tn * 16 + ln) * 16);
#pragma unroll
      for (int tm = 0; tm < 4; ++tm)
#pragma unroll
        for (int tn = 0; tn < 4; ++tn)
          acc[tm][tn] = __builtin_amdgcn_mfma_f32_16x16x32_bf16(af[tm], bfr[tn], acc[tm][tn], 0, 0, 0);
    }
    __syncthreads();
  }

#pragma unroll
  for (int tm = 0; tm < 4; ++tm) {
    int mb = m0 + wm * 64 + tm * 16 + quad * 4;
#pragma unroll
    for (int tn = 0; tn < 4; ++tn) {
      int n = n0 + wn * 64 + tn * 16 + ln;
      float bn = (MODE == 0) ? bias[n] : 0.f;
#pragma unroll
      for (int r = 0; r < 4; ++r) {
        int m = mb + r;
        float v = acc[tm][tn][r];
        if (MODE == 0) {
          ((u16*)out)[(size_t)m * ostr + n] = f2bf(v + bn);
        } else if (MODE == 1) {
          ((u16*)out)[(size_t)m * ostr + n] = f2bf(v + bias[m]);
        } else {
          int bb = n >> 12, nn = n & 4095;
          size_t off = ((size_t)(bb * 512 + m)) * 4096 + nn;
          ((float*)out)[off] = v + bias[m] + res[off];
        }
      }
    }
  }
}

// ---------------------------------------------------------------------------
// Flash attention, bf16 MFMA. Block: 512 thr (8 waves), BI=32 query rows,
// BJ=512 key block. Per wave: S strip [32 i][64 j] (2x4 tiles), O strip
// [32 i][64 c] (2x4 tiles, c = w*64..). Online softmax in fp32.
// LDS: Qs 4K (per-cstep chunk, aliased w/ smax/ssum) | KVs 64K | Ps 32K.
// ---------------------------------------------------------------------------
__global__ __launch_bounds__(512) void flash_mfma(
    const u16* __restrict__ QKt, const u16* __restrict__ Vg,
    u16* __restrict__ AOt) {
  __shared__ char smbuf[102784];
  char* Qs = smbuf;                        // 4 KB [kc8][i32]
  char* KVs = smbuf + 4096;                // 64 KB: K [kc8][j512] / V [kc8][c512]
  char* Ps = smbuf + 69632;                // 32 KB [kcj64][i32]
  float* rowm = (float*)(smbuf + 102400);  // [32] persist
  float* rowa = rowm + 32;
  float* rowl = rowa + 32;
  float* smax = (float*)Qs;                // [8][32] alias (Qs dead at softmax)
  float* ssum = smax + 256;

  int t = threadIdx.x;
  int w = t >> 6, lane = t & 63, quad = lane >> 4, ln = lane & 15;
  int b = blockIdx.y;
  int i0 = blockIdx.x * 32;
  size_t prow0 = (size_t)b * 4096 + i0;

  if (t < 32) { rowm[t] = -1e30f; rowl[t] = 0.f; }
  f32x4 o[2][4] = {};  // i = tm*16+quad*4+r, c = w*64+tn*16+ln

  int krow[8], kkc[8];
#pragma unroll
  for (int si = 0; si < 8; ++si) {
    int s = (w * 8 + si) * 64 + lane;
    krow[si] = s & 511;
    kkc[si] = s >> 9;
  }
  int qi = (w * 64 + lane) & 31, qkc = (w * 64 + lane) >> 5;

  __syncthreads();

  for (int j0 = 0; j0 < 4096; j0 += 512) {
    // ---------------- S = (Q K^T) * scale ----------------
    f32x4 sacc[2][4] = {};
    for (int cst = 0; cst < 8; ++cst) {
      if (w < 4)
        gll16(QKt + (prow0 + qi) * 1024 + cst * 64 + qkc * 8, Qs + w * 1024);
#pragma unroll
      for (int si = 0; si < 8; ++si)
        gll16(QKt + ((size_t)b * 4096 + j0 + krow[si]) * 1024 + 512 + cst * 64 + kkc[si] * 8,
              KVs + (w * 8 + si) * 1024);
      __syncthreads();
#pragma unroll
      for (int ks = 0; ks < 2; ++ks) {
        bf16x8 aq[2], bk_[4];
#pragma unroll
        for (int tm = 0; tm < 2; ++tm)
          aq[tm] = *(const bf16x8*)(Qs + (((ks * 4 + quad) * 32) + tm * 16 + ln) * 16);
#pragma unroll
        for (int tn = 0; tn < 4; ++tn)
          bk_[tn] = *(const bf16x8*)(KVs + (((ks * 4 + quad) * 512) + w * 64 + tn * 16 + ln) * 16);
#pragma unroll
        for (int tm = 0; tm < 2; ++tm)
#pragma unroll
          for (int tn = 0; tn < 4; ++tn)
            sacc[tm][tn] = __builtin_amdgcn_mfma_f32_16x16x32_bf16(aq[tm], bk_[tn], sacc[tm][tn], 0, 0, 0);
      }
      __syncthreads();
    }
#pragma unroll
    for (int tm = 0; tm < 2; ++tm)
#pragma unroll
      for (int tn = 0; tn < 4; ++tn)
#pragma unroll
        for (int r = 0; r < 4; ++r) sacc[tm][tn][r] *= 0.044194173824159216f;

    // ---------------- online softmax ----------------
    float mx[2][4];
#pragma unroll
    for (int tm = 0; tm < 2; ++tm)
#pragma unroll
      for (int r = 0; r < 4; ++r) {
        float m_ = fmaxf(fmaxf(sacc[tm][0][r], sacc[tm][1][r]),
                         fmaxf(sacc[tm][2][r], sacc[tm][3][r]));
#pragma unroll
        for (int d = 1; d < 16; d <<= 1) m_ = fmaxf(m_, __shfl_xor(m_, d));
        mx[tm][r] = m_;
      }
    if (ln == 0) {
#pragma unroll
      for (int tm = 0; tm < 2; ++tm)
#pragma unroll
        for (int r = 0; r < 4; ++r) smax[w * 32 + tm * 16 + quad * 4 + r] = mx[tm][r];
    }
    __syncthreads();
    if (t < 32) {
      float m_ = smax[t];
#pragma unroll
      for (int ww = 1; ww < 8; ++ww) m_ = fmaxf(m_, smax[ww * 32 + t]);
      float mold = rowm[t];
      float mnew = fmaxf(mold, m_);
      rowm[t] = mnew;
      rowa[t] = __expf(mold - mnew);
    }
    __syncthreads();
    float su[2][4], al[2][4];
#pragma unroll
    for (int tm = 0; tm < 2; ++tm)
#pragma unroll
      for (int r = 0; r < 4; ++r) {
        int i = tm * 16 + quad * 4 + r;
        float mrow = rowm[i];
        float sm_ = 0.f;
#pragma unroll
        for (int tn = 0; tn < 4; ++tn) {
          float p = __expf(sacc[tm][tn][r] - mrow);
          sm_ += p;
          int j = w * 64 + tn * 16 + ln;
          *(u16*)(Ps + ((size_t)(j >> 3) * 32 + i) * 16 + (j & 7) * 2) = f2bf(p);
        }
#pragma unroll
        for (int d = 1; d < 16; d <<= 1) sm_ += __shfl_xor(sm_, d);
        su[tm][r] = sm_;
        al[tm][r] = rowa[i];
      }
    if (ln == 0) {
#pragma unroll
      for (int tm = 0; tm < 2; ++tm)
#pragma unroll
        for (int r = 0; r < 4; ++r) ssum[w * 32 + tm * 16 + quad * 4 + r] = su[tm][r];
    }
#pragma unroll
    for (int tm = 0; tm < 2; ++tm)
#pragma unroll
      for (int tn = 0; tn < 4; ++tn)
#pragma unroll
        for (int r = 0; r < 4; ++r) o[tm][tn][r] *= al[tm][r];
    __syncthreads();  // Ps + ssum complete; KVs free for V
    if (t < 32) {
      float a_ = 0.f;
#pragma unroll
      for (int ww = 0; ww < 8; ++ww) a_ += ssum[ww * 32 + t];
      rowl[t] = rowl[t] * rowa[t] + a_;
    }

    // ---------------- O += P V^T ----------------
    for (int jh = 0; jh < 8; ++jh) {
#pragma unroll
      for (int si = 0; si < 8; ++si)
        gll16(Vg + (size_t)krow[si] * 8192 + (size_t)b * 4096 + j0 + jh * 64 + kkc[si] * 8,
              KVs + (w * 8 + si) * 1024);
      __syncthreads();
#pragma unroll
      for (int ks = 0; ks < 2; ++ks) {
        bf16x8 ap[2], bv_[4];
#pragma unroll
        for (int tm = 0; tm < 2; ++tm)
          ap[tm] = *(const bf16x8*)(Ps + ((size_t)(jh * 8 + ks * 4 + quad) * 32 + tm * 16 + ln) * 16);
#pragma unroll
        for (int tn = 0; tn < 4; ++tn)
          bv_[tn] = *(const bf16x8*)(KVs + (((ks * 4 + quad) * 512) + w * 64 + tn * 16 + ln) * 16);
#pragma unroll
        for (int tm = 0; tm < 2; ++tm)
#pragma unroll
          for (int tn = 0; tn < 4; ++tn)
            o[tm][tn] = __builtin_amdgcn_mfma_f32_16x16x32_bf16(ap[tm], bv_[tn], o[tm][tn], 0, 0, 0);
      }
      __syncthreads();
    }
  }

  __syncthreads();
  if (t < 32) rowa[t] = 1.f / rowl[t];
  __syncthreads();
#pragma unroll
  for (int tm = 0; tm < 2; ++tm)
#pragma unroll
    for (int r = 0; r < 4; ++r) {
      int i = tm * 16 + quad * 4 + r;
      float inv = rowa[i];
#pragma unroll
      for (int tn = 0; tn < 4; ++tn) {
        int c = w * 64 + tn * 16 + ln;
        AOt[(prow0 + i) * 512 + c] = f2bf(o[tm][tn][r] * inv);
      }
    }
}

// ---------------------------------------------------------------------------
extern "C" void kernel_launch(void* const* d_in, const int* in_sizes, int n_in,
                              void* d_out, int out_size, void* d_ws, size_t ws_size,
                              hipStream_t stream) {
  (void)in_sizes; (void)n_in; (void)out_size; (void)ws_size;
  const float* x = (const float*)d_in[0];
  const float* gnw = (const float*)d_in[1];
  const float* gnb = (const float*)d_in[2];
  const float* wq = (const float*)d_in[3];
  const float* bq = (const float*)d_in[4];
  const float* wk = (const float*)d_in[5];
  const float* bk = (const float*)d_in[6];
  const float* wv = (const float*)d_in[7];
  const float* bv = (const float*)d_in[8];
  const float* wo = (const float*)d_in[9];
  const float* bo = (const float*)d_in[10];
  float* out = (float*)d_out;

  char* ws = (char*)d_ws;
  u16* ht  = (u16*)(ws);
  u16* QKt = (u16*)(ws + 8388608);
  u16* Vg  = (u16*)(ws + 25165824);
  u16* AOt = (u16*)(ws + 33554432);
  u16* Wqk = (u16*)(ws + 41943040);
  u16* Wv  = (u16*)(ws + 42991616);
  u16* Wo  = (u16*)(ws + 43515904);
  float* Bqk = (float*)(ws + 44040192);

  wcvt_kernel<<<1024, 256, 0, stream>>>(wq, wk, wv, wo, bq, bk, Wqk, Wv, Wo, Bqk);
  gn_kernel<<<64, 256, 0, stream>>>(x, gnw, gnb, ht);
  // q|k = ht * Wqk^T  -> [pix][1024]
  mfma_gemm<0><<<dim3(8, 64), 256, 0, stream>>>(ht, 512, Wqk, 512, Bqk, nullptr, QKt, 1024);
  // v = Wv * ht^T -> [c][pix]
  mfma_gemm<1><<<dim3(64, 4), 256, 0, stream>>>(Wv, 512, ht, 512, bv, nullptr, Vg, 8192);
  flash_mfma<<<dim3(128, 2), 512, 0, stream>>>(QKt, Vg, AOt);
  // out = x + Wo * AO^T + bo -> fp32 [b][c][n]
  mfma_gemm<2><<<dim3(64, 4), 256, 0, stream>>>(Wo, 512, AOt, 512, bo, x, out, 0);
}